// Round 2
// baseline (536.344 us; speedup 1.0000x reference)
//
#include <hip/hip_runtime.h>

// Problem constants (from reference):
//   x: (4096, 16) int32 indices in [0, 100000)
//   W: (16, 100000, 64) float32
//   out: (4096, 8704) float32
//     out[b, p*64+d]        = W[jj[p], x[b,ii[p]], d] * W[ii[p], x[b,jj[p]], d]  (p < 120 triu pairs)
//     out[b, 7680 + f*64+d] = W[f, x[b,f], d]                                    (16 diag rows)
#define FEAT   100000
#define NFIELD 16
#define DIM    64
#define BATCH  4096
#define NPAIR  120
#define NROWS  136              // 120 pairs + 16 diag rows per batch element
#define OUTB   (NROWS * DIM)    // 8704 floats per batch element

__global__ __launch_bounds__(256) void ffm_gather_kernel(
        const int*   __restrict__ x,
        const float* __restrict__ W,
        float*       __restrict__ out)
{
    // One thread per float4 of output.
    int idx  = blockIdx.x * 256 + threadIdx.x;     // [0, BATCH*NROWS*16)
    int dq   = idx & 15;                           // which float4 within the 64-float row
    int rest = idx >> 4;                           // b * NROWS + p
    int p    = rest % NROWS;
    int b    = rest / NROWS;
    if (b >= BATCH) return;

    int i, j;
    if (p < NPAIR) {
        // decode triu pair p -> (i, j), row-major triu order (i < j)
        int s = 0;
        i = 0;
        while (p >= s + (NFIELD - 1 - i)) { s += NFIELD - 1 - i; ++i; }
        j = i + 1 + (p - s);
    } else {
        i = j = p - NPAIR;                         // diag row
    }

    int fi = x[b * NFIELD + i];                    // feature of field i
    // Row A: field i's feature looked up in table j  -> W[j, fi, :]
    const float4* rowA = (const float4*)(W + ((size_t)(j * FEAT + fi)) * DIM);
    float4 a = rowA[dq];

    float4 v;
    if (p < NPAIR) {
        int fj = x[b * NFIELD + j];
        // Row B: field j's feature looked up in table i -> W[i, fj, :]
        const float4* rowB = (const float4*)(W + ((size_t)(i * FEAT + fj)) * DIM);
        float4 bb = rowB[dq];
        v = make_float4(a.x * bb.x, a.y * bb.y, a.z * bb.z, a.w * bb.w);
    } else {
        v = a;                                     // diag: plain copy of embedding
    }

    ((float4*)out)[idx] = v;
}

extern "C" void kernel_launch(void* const* d_in, const int* in_sizes, int n_in,
                              void* d_out, int out_size, void* d_ws, size_t ws_size,
                              hipStream_t stream)
{
    const int*   x = (const int*)  d_in[0];
    const float* W = (const float*)d_in[1];
    float*     out = (float*)      d_out;

    const int total_f4 = BATCH * NROWS * 16;       // 8,912,896 threads
    const int blocks   = (total_f4 + 255) / 256;   // 34,816 (exact)
    ffm_gather_kernel<<<blocks, 256, 0, stream>>>(x, W, out);
}

// Round 6
// 534.371 us; speedup vs baseline: 1.0037x; 1.0037x over previous
//
#include <hip/hip_runtime.h>

// Problem constants (from reference):
//   x: (4096, 16) int32 indices in [0, 100000)
//   W: (16, 100000, 64) float32
//   out: (4096, 8704) float32
//     out[b, p*64+d]        = W[jj[p], x[b,ii[p]], d] * W[ii[p], x[b,jj[p]], d]  (p < 120 triu pairs)
//     out[b, 7680 + f*64+d] = W[f, x[b,f], d]                                    (16 diag rows)
#define FEAT   100000
#define NFIELD 16
#define DIM    64
#define BATCH  4096
#define NPAIR  120
#define NROWS  136              // 120 pairs + 16 diag rows per batch element
#define OUTB   (NROWS * DIM)    // 8704 floats per batch element

// Native clang vector type — __builtin_nontemporal_store requires this
// (HIP's float4 is a struct and is rejected).
typedef float f32x4 __attribute__((ext_vector_type(4)));

// Packed (i<<4)|j for the 120 row-major triu pairs, then 16 diag entries.
__constant__ unsigned char PAIR_LUT[NROWS] = {
    // i=0, j=1..15
    0x01,0x02,0x03,0x04,0x05,0x06,0x07,0x08,0x09,0x0A,0x0B,0x0C,0x0D,0x0E,0x0F,
    // i=1, j=2..15
    0x12,0x13,0x14,0x15,0x16,0x17,0x18,0x19,0x1A,0x1B,0x1C,0x1D,0x1E,0x1F,
    // i=2
    0x23,0x24,0x25,0x26,0x27,0x28,0x29,0x2A,0x2B,0x2C,0x2D,0x2E,0x2F,
    // i=3
    0x34,0x35,0x36,0x37,0x38,0x39,0x3A,0x3B,0x3C,0x3D,0x3E,0x3F,
    // i=4
    0x45,0x46,0x47,0x48,0x49,0x4A,0x4B,0x4C,0x4D,0x4E,0x4F,
    // i=5
    0x56,0x57,0x58,0x59,0x5A,0x5B,0x5C,0x5D,0x5E,0x5F,
    // i=6
    0x67,0x68,0x69,0x6A,0x6B,0x6C,0x6D,0x6E,0x6F,
    // i=7
    0x78,0x79,0x7A,0x7B,0x7C,0x7D,0x7E,0x7F,
    // i=8
    0x89,0x8A,0x8B,0x8C,0x8D,0x8E,0x8F,
    // i=9
    0x9A,0x9B,0x9C,0x9D,0x9E,0x9F,
    // i=10
    0xAB,0xAC,0xAD,0xAE,0xAF,
    // i=11
    0xBC,0xBD,0xBE,0xBF,
    // i=12
    0xCD,0xCE,0xCF,
    // i=13
    0xDE,0xDF,
    // i=14
    0xEF,
    // diag f=0..15
    0x00,0x11,0x22,0x33,0x44,0x55,0x66,0x77,0x88,0x99,0xAA,0xBB,0xCC,0xDD,0xEE,0xFF
};

__global__ __launch_bounds__(256) void ffm_gather_kernel(
        const int*   __restrict__ x,
        const float* __restrict__ W,
        float*       __restrict__ out)
{
    // One thread per float4 of output.
    int idx  = blockIdx.x * 256 + threadIdx.x;     // [0, BATCH*NROWS*16)
    int dq   = idx & 15;                           // which float4 within the 64-float row
    int rest = idx >> 4;                           // b * NROWS + p
    int p    = rest % NROWS;
    int b    = rest / NROWS;
    if (b >= BATCH) return;

    int ij = PAIR_LUT[p];
    int i  = ij >> 4;
    int j  = ij & 15;

    int fi = x[b * NFIELD + i];                    // feature of field i
    // Row A: field i's feature looked up in table j  -> W[j, fi, :]
    const f32x4* rowA = (const f32x4*)(W + ((size_t)(j * FEAT + fi)) * DIM);
    f32x4 a = rowA[dq];

    f32x4 v;
    if (p < NPAIR) {
        int fj = x[b * NFIELD + j];
        // Row B: field j's feature looked up in table i -> W[i, fj, :]
        const f32x4* rowB = (const f32x4*)(W + ((size_t)(i * FEAT + fj)) * DIM);
        f32x4 bb = rowB[dq];
        v = a * bb;
    } else {
        v = a;                                     // diag: plain copy of embedding
    }

    // Streaming store: bypass L2/L3 so the gathered W rows (which have ~1.35x
    // reuse and a ~197 MB distinct footprint vs 256 MB L3) stay cached.
    __builtin_nontemporal_store(v, (f32x4*)out + idx);
}

extern "C" void kernel_launch(void* const* d_in, const int* in_sizes, int n_in,
                              void* d_out, int out_size, void* d_ws, size_t ws_size,
                              hipStream_t stream)
{
    const int*   x = (const int*)  d_in[0];
    const float* W = (const float*)d_in[1];
    float*     out = (float*)      d_out;

    const int total_f4 = BATCH * NROWS * 16;       // 8,912,896 threads
    const int blocks   = (total_f4 + 255) / 256;   // 34,816 (exact)
    ffm_gather_kernel<<<blocks, 256, 0, stream>>>(x, W, out);
}